// Round 6
// baseline (236.710 us; speedup 1.0000x reference)
//
#include <hip/hip_runtime.h>

// WaveCell: y = denom * (2/dt^2 * y1 - (1/dt^2 - b/dt) * y2 + c^2 * lap(y1))
// denom = 1 / (1/dt^2 + b/dt); lap = 5-point stencil with zero padding, / h^2.
// Outputs: (y, y1) concatenated flat in d_out.
//
// R6: 4-row vertical coarsening (4x4 tile/thread) — 6 y1-row loads serve 4
//     output rows (1.5/row vs 2.0), ~22 vec4 loads in flight per thread.
//     Keeps XCD-contiguous bijective swizzle + NT stores, normal loads.
//     __launch_bounds__(256,4) caps VGPR at 128 to hold 4 waves/SIMD.

#define WAVE_DT 0.001f
#define WAVE_H  10.0f

typedef float fvec4 __attribute__((ext_vector_type(4)));

__global__ __launch_bounds__(256, 4) void WaveCell_790273982844_kernel(
    const float* __restrict__ c,
    const float* __restrict__ b,
    const float* __restrict__ y1,
    const float* __restrict__ y2,
    float* __restrict__ out_y,
    float* __restrict__ out_y1)
{
    constexpr int W  = 4096;
    constexpr int H  = 4096;
    constexpr int W4 = W / 4;            // 1024 float4 per row
    constexpr int HQ = H / 4;            // 1024 row-quads per image

    const float inv_dt2 = 1.0f / (WAVE_DT * WAVE_DT);  // 1e6
    const float inv_dt  = 1.0f / WAVE_DT;              // 1e3
    const float inv_h2  = 1.0f / (WAVE_H * WAVE_H);    // 0.01

    // XCD-contiguous bijective swizzle (nwg = 16384, divisible by 8).
    const unsigned nwg = gridDim.x;
    const unsigned cpx = nwg >> 3;
    const unsigned bid = blockIdx.x;
    const unsigned swz = (bid & 7u) * cpx + (bid >> 3);

    const long t       = (long)swz * blockDim.x + threadIdx.x;
    const int  j4      = (int)(t & (W4 - 1));
    const long quadIdx = t >> 10;                    // 0 .. B*HQ-1
    const int  iq      = (int)(quadIdx & (HQ - 1));  // quad within image
    const long batch   = quadIdx >> 10;              // HQ = 1024 -> shift 10
    const int  i       = iq << 2;                    // first of 4 rows
    const int  j       = j4 << 2;

    const long base = (batch * H + i) * (long)W;     // flat index of row i
    const float* r0 = y1 + base;                     // y1 row i
    const float* q0 = y2 + base;                     // y2 row i
    const float* c0 = c + (long)i * W;               // c row i
    const float* b0 = b + (long)i * W;               // b row i

    const fvec4 zero = (fvec4)0.0f;

    // y1 rows i-1 .. i+4 (6 vector loads serve 4 output rows)
    fvec4 vy[6];
    vy[0] = (i > 0)     ? *(const fvec4*)(r0 - W + j)     : zero;
    vy[1] = *(const fvec4*)(r0 + j);
    vy[2] = *(const fvec4*)(r0 + W + j);
    vy[3] = *(const fvec4*)(r0 + 2 * (long)W + j);
    vy[4] = *(const fvec4*)(r0 + 3 * (long)W + j);
    vy[5] = (i + 4 < H) ? *(const fvec4*)(r0 + 4 * (long)W + j) : zero;

    float lf[4], rt[4];
#pragma unroll
    for (int r = 0; r < 4; ++r) {
        lf[r] = (j > 0)     ? r0[(long)r * W + j - 1] : 0.0f;
        rt[r] = (j + 4 < W) ? r0[(long)r * W + j + 4] : 0.0f;
    }

    fvec4 p2v[4], ccv[4], bbv[4];
#pragma unroll
    for (int r = 0; r < 4; ++r) {
        p2v[r] = *(const fvec4*)(q0 + (long)r * W + j);
        ccv[r] = *(const fvec4*)(c0 + (long)r * W + j);
        bbv[r] = *(const fvec4*)(b0 + (long)r * W + j);
    }

#pragma unroll
    for (int r = 0; r < 4; ++r) {
        const fvec4 ce = vy[r + 1];
        const fvec4 up = vy[r];
        const fvec4 dn = vy[r + 2];
        const float le[4] = {lf[r], ce.x, ce.y, ce.z};
        const float re[4] = {ce.y, ce.z, ce.w, rt[r]};

        fvec4 yo;
#pragma unroll
        for (int k = 0; k < 4; ++k) {
            const float lap   = (up[k] + dn[k] + le[k] + re[k] - 4.0f * ce[k]) * inv_h2;
            const float bdt   = bbv[r][k] * inv_dt;
            const float denom = 1.0f / (inv_dt2 + bdt);
            yo[k] = denom * (2.0f * inv_dt2 * ce[k]
                             - (inv_dt2 - bdt) * p2v[r][k]
                             + ccv[r][k] * ccv[r][k] * lap);
        }

        __builtin_nontemporal_store(yo, (fvec4*)(out_y  + base + (long)r * W + j));
        __builtin_nontemporal_store(ce, (fvec4*)(out_y1 + base + (long)r * W + j));
    }
}

extern "C" void kernel_launch(void* const* d_in, const int* in_sizes, int n_in,
                              void* d_out, int out_size, void* d_ws, size_t ws_size,
                              hipStream_t stream) {
    (void)in_sizes; (void)n_in; (void)d_ws; (void)ws_size; (void)out_size;

    const float* c  = (const float*)d_in[0];
    const float* b  = (const float*)d_in[1];
    const float* y1 = (const float*)d_in[2];
    const float* y2 = (const float*)d_in[3];

    const long B = 4, H = 4096, W = 4096;
    const long N = B * H * W;                 // 67,108,864 elements per field

    float* out_y  = (float*)d_out;
    float* out_y1 = out_y + N;

    const long totalThreads = N / 16;         // one (4-row x float4) tile per thread
    const int  block = 256;
    const long grid  = totalThreads / block;  // 16384

    WaveCell_790273982844_kernel<<<(unsigned)grid, block, 0, stream>>>(
        c, b, y1, y2, out_y, out_y1);
}